// Round 7
// baseline (174.115 us; speedup 1.0000x reference)
//
#include <hip/hip_runtime.h>

typedef __attribute__((ext_vector_type(4))) float f32x4;
typedef __attribute__((ext_vector_type(8))) short s16x8;

#define GLDS(gsrc, ldst) \
  __builtin_amdgcn_global_load_lds((const __attribute__((address_space(1))) void*)(gsrc), \
                                   (__attribute__((address_space(3))) void*)(ldst), 16, 0, 0)

__device__ __forceinline__ ushort f2bf(float f) {
  union { float f; unsigned u; } x; x.f = f;
  unsigned r = (x.u + 0x7FFFu + ((x.u >> 16) & 1u)) >> 16;
  return (ushort)r;
}

template<int N> __device__ __forceinline__ void waitvm() {
  if constexpr (N == 0) asm volatile("s_waitcnt vmcnt(0)" ::: "memory");
  else if constexpr (N == 4) asm volatile("s_waitcnt vmcnt(4)" ::: "memory");
  else if constexpr (N == 8) asm volatile("s_waitcnt vmcnt(8)" ::: "memory");
}

// ---------------- cast f32 -> bf16 ----------------
__global__ __launch_bounds__(256) void castk(const float* __restrict__ in,
                                             ushort* __restrict__ outp, int n) {
  int i = (blockIdx.x * 256 + threadIdx.x) * 4;
  if (i >= n) return;
  float4 v = *(const float4*)(in + i);
  ushort4 r;
  r.x = f2bf(v.x); r.y = f2bf(v.y); r.z = f2bf(v.z); r.w = f2bf(v.w);
  *(ushort4*)(outp + i) = r;
}

__global__ __launch_bounds__(256) void castw(const float* __restrict__ w0, const float* __restrict__ w1,
                                             const float* __restrict__ w2, const float* __restrict__ w3,
                                             ushort* __restrict__ o0, ushort* __restrict__ o1,
                                             ushort* __restrict__ o2, ushort* __restrict__ o3) {
  int bid = blockIdx.x;
  int sel = bid >> 10;
  const float* in = (sel == 0) ? w0 : (sel == 1) ? w1 : (sel == 2) ? w2 : w3;
  ushort* outp    = (sel == 0) ? o0 : (sel == 1) ? o1 : (sel == 2) ? o2 : o3;
  int i = ((bid & 1023) * 256 + threadIdx.x) * 4;
  float4 v = *(const float4*)(in + i);
  ushort4 r;
  r.x = f2bf(v.x); r.y = f2bf(v.y); r.z = f2bf(v.z); r.w = f2bf(v.w);
  *(ushort4*)(outp + i) = r;
}

// ---------------- GEMM 256x256, quadrant 8-phase, BK=64 ----------------
// C[M,N] = A[M,K]*Bt[N,K]^T + bias. 512 thr = 8 waves. Per-quadrant wave grid 2x4,
// per-wave-per-quadrant 64x32 (4mf x 2nf). Gray quadrant order (00,01,11,10); B(qn0)
// frags held ph1->ph4. LDS 128KB = 2 buf x (A 256x64 + B 256x64) bf16, granule-swizzled
// (slot = g ^ (r&7), pre-swizzled source). Stage halves (2 glds) per phase in the
// phase after the region dies; vmcnt(4) at ph4/ph8 (derived), vmcnt(0) on last iter.
template<int OUTBF16>
__global__ __launch_bounds__(512) void gemmQ(
    const ushort* __restrict__ A, const ushort* __restrict__ Bt,
    const float* __restrict__ bias0, const float* __restrict__ bias1,
    const float* __restrict__ bias2,
    void* __restrict__ Cout, int M, int N, int K, int nxn)
{
  constexpr int SB = 32768;  // buffer stride (ushorts): A 16384 + B 16384
  __shared__ __align__(16) ushort lds[65536];

  const int tid = threadIdx.x;
  const int w = tid >> 6, lane = tid & 63;
  const int lrow = lane & 15, lg = lane >> 4;
  const int wm2a = (w >> 2) * 64, wn2a = (w & 3) * 32;
  const int cpx = gridDim.x >> 3;
  const int wgid = ((int)blockIdx.x & 7) * cpx + ((int)blockIdx.x >> 3);
  const int mblk = (wgid / nxn) * 256;
  const int nblk = (wgid % nxn) * 256;
  const int NT = K >> 6, NI = NT >> 1;

  // staging: thread t covers row (t>>3) [+64 for 2nd issue], slot t&7, src granule pre-swizzled
  const int sg8 = 8 * ((tid & 7) ^ ((tid >> 3) & 7));
  const ushort* As0 = A + (size_t)(mblk + (tid >> 3)) * K + sg8;
  const ushort* Bs0 = Bt + (size_t)(nblk + (tid >> 3)) * K + sg8;
  const size_t r64 = (size_t)64 * K;
  const int wl512 = w * 512;

  auto stage = [&](int isB, int kt, int half, int bufb) {
    const ushort* s = (isB ? Bs0 : As0) + (size_t)kt * 64 + (size_t)(half * 128) * K;
    const int d = bufb + isB * 16384 + half * 8192 + wl512;
    GLDS(s, &lds[d]);
    GLDS(s + r64, &lds[d + 4096]);
  };

  // ds-read bases (ushort idx)
  const int axk0 = ((lg) ^ (lrow & 7)) << 3;
  const int axk1 = ((4 + lg) ^ (lrow & 7)) << 3;
  const int arow = (wm2a + lrow) * 64;
  const int brow = 16384 + (wn2a + lrow) * 64;

  s16x8 af[4][2], bf0[2][2], bf1[2][2];
  const f32x4 zero = {0.f, 0.f, 0.f, 0.f};
  f32x4 acc[2][2][4][2];
#pragma unroll
  for (int qm = 0; qm < 2; qm++)
#pragma unroll
    for (int qn = 0; qn < 2; qn++)
#pragma unroll
      for (int mf = 0; mf < 4; mf++)
#pragma unroll
        for (int nf = 0; nf < 2; nf++) acc[qm][qn][mf][nf] = zero;

#define LOADA(qm, bb) { \
  _Pragma("unroll") for (int mf = 0; mf < 4; mf++) { \
    af[mf][0] = *(const s16x8*)&lds[(bb) + (qm) * 8192 + arow + mf * 1024 + axk0]; \
    af[mf][1] = *(const s16x8*)&lds[(bb) + (qm) * 8192 + arow + mf * 1024 + axk1]; } }
#define LOADB(qn, bb, bfr) { \
  _Pragma("unroll") for (int nf = 0; nf < 2; nf++) { \
    bfr[nf][0] = *(const s16x8*)&lds[(bb) + (qn) * 8192 + brow + nf * 1024 + axk0]; \
    bfr[nf][1] = *(const s16x8*)&lds[(bb) + (qn) * 8192 + brow + nf * 1024 + axk1]; } }
#define MMA(qm, qn, bfr) { \
  __builtin_amdgcn_s_setprio(1); \
  _Pragma("unroll") for (int mf = 0; mf < 4; mf++) \
    _Pragma("unroll") for (int nf = 0; nf < 2; nf++) { \
      acc[qm][qn][mf][nf] = __builtin_amdgcn_mfma_f32_16x16x32_bf16(af[mf][0], bfr[nf][0], acc[qm][qn][mf][nf], 0, 0, 0); \
      acc[qm][qn][mf][nf] = __builtin_amdgcn_mfma_f32_16x16x32_bf16(af[mf][1], bfr[nf][1], acc[qm][qn][mf][nf], 0, 0, 0); } \
  __builtin_amdgcn_s_setprio(0); }
#define BAR() __builtin_amdgcn_s_barrier()

  // prologue: tile 0 -> buf0 (first 8 loads), tile 1 -> buf1
  stage(0, 0, 0, 0);  stage(0, 0, 1, 0);  stage(1, 0, 0, 0);  stage(1, 0, 1, 0);
  stage(0, 1, 0, SB); stage(0, 1, 1, SB); stage(1, 1, 0, SB); stage(1, 1, 1, SB);
  waitvm<8>(); BAR();

  for (int it = 0; it < NI; ++it) {
    const bool sB1 = (it > 0);
    const bool sA2 = (2 * it + 2 < NT);
    const bool sB2 = (2 * it + 3 < NT);
    const int kb1 = 2 * it + 1, ka2 = 2 * it + 2, kb2 = 2 * it + 3;

    // ---- buf0 tile (2*it) ----
    // ph1: Q(0,0)
    LOADA(0, 0); LOADB(0, 0, bf0);
    if (sB1) stage(0, kb1, 1, SB);        // Ah1(b1) -> buf1
    BAR(); MMA(0, 0, bf0); BAR();
    // ph2: Q(0,1)
    LOADB(1, 0, bf1);
    if (sB1) stage(1, kb1, 0, SB);        // Bh0(b1) -> buf1
    BAR(); MMA(0, 1, bf1); BAR();
    // ph3: Q(1,1)
    LOADA(1, 0);
    if (sA2) stage(0, ka2, 0, 0);         // Ah0(a2) -> buf0
    BAR(); MMA(1, 1, bf1);
    BAR();
    // ph4: Q(1,0)  (no ds reads; bf0 held)
    if (sA2) stage(1, ka2, 1, 0);         // Bh1(a2) -> buf0
    BAR(); MMA(1, 0, bf0);
    if (it == NI - 1) waitvm<0>(); else waitvm<4>();
    BAR();

    // ---- buf1 tile (2*it+1) ----
    // ph5: Q(0,0)
    LOADA(0, SB); LOADB(0, SB, bf0);
    if (sA2) stage(0, ka2, 1, 0);         // Ah1(a2) -> buf0
    BAR(); MMA(0, 0, bf0); BAR();
    // ph6: Q(0,1)
    LOADB(1, SB, bf1);
    if (sA2) stage(1, ka2, 0, 0);         // Bh0(a2) -> buf0
    BAR(); MMA(0, 1, bf1); BAR();
    // ph7: Q(1,1)
    LOADA(1, SB);
    if (sB2) stage(0, kb2, 0, SB);        // Ah0(b2) -> buf1
    BAR(); MMA(1, 1, bf1); BAR();
    // ph8: Q(1,0)
    if (sB2) stage(1, kb2, 1, SB);        // Bh1(b2) -> buf1
    BAR(); MMA(1, 0, bf0);
    if (it + 1 < NI) {
      if (it + 1 == NI - 1) waitvm<0>(); else waitvm<4>();
      BAR();
    }
  }
#undef LOADA
#undef LOADB
#undef MMA
#undef BAR

  // bias per (qn, nf) column
  float bias_n[2][2];
#pragma unroll
  for (int qn = 0; qn < 2; qn++)
#pragma unroll
    for (int nf = 0; nf < 2; nf++) {
      const int col = nblk + qn * 128 + wn2a + nf * 16 + lrow;
      if (bias1) bias_n[qn][nf] = (col < 1024) ? bias0[col]
                                 : (col < 2048 ? bias1[col - 1024] : bias2[col - 2048]);
      else bias_n[qn][nf] = bias0[col];
    }

  __syncthreads();   // all LDS traffic done; reuse LDS as C staging

  if constexpr (OUTBF16) {
    ushort* Ct = lds;  // [256][256] bf16 = 128KB, exact fit
#pragma unroll
    for (int qm = 0; qm < 2; qm++)
#pragma unroll
      for (int qn = 0; qn < 2; qn++)
#pragma unroll
        for (int mf = 0; mf < 4; mf++)
#pragma unroll
          for (int nf = 0; nf < 2; nf++) {
            f32x4 v = acc[qm][qn][mf][nf];
#pragma unroll
            for (int i = 0; i < 4; i++)
              Ct[(qm * 128 + wm2a + mf * 16 + 4 * lg + i) * 256 +
                 qn * 128 + wn2a + nf * 16 + lrow] = f2bf(v[i] + bias_n[qn][nf]);
          }
    __syncthreads();
    ushort* Cg = (ushort*)Cout;
#pragma unroll
    for (int p = 0; p < 16; p++) {
      const unsigned g = p * 512 + tid;
      const unsigned row = g >> 5, c8 = g & 31;
      *(s16x8*)&Cg[(size_t)(mblk + row) * N + nblk + c8 * 8] = *(const s16x8*)&lds[g * 8];
    }
  } else {
    float* Cf = (float*)lds;  // [64][256] f32 = 64KB chunk
    float* Cg = (float*)Cout;
#pragma unroll
    for (int c = 0; c < 4; c++) {
      __syncthreads();
      if ((w >> 2) == (c & 1)) {
        const int qm = c >> 1;
#pragma unroll
        for (int qn = 0; qn < 2; qn++)
#pragma unroll
          for (int mf = 0; mf < 4; mf++)
#pragma unroll
            for (int nf = 0; nf < 2; nf++) {
              f32x4 v = acc[qm][qn][mf][nf];
#pragma unroll
              for (int i = 0; i < 4; i++)
                Cf[(mf * 16 + 4 * lg + i) * 256 + qn * 128 + wn2a + nf * 16 + lrow] =
                    v[i] + bias_n[qn][nf];
            }
      }
      __syncthreads();
#pragma unroll
      for (int p = 0; p < 8; p++) {
        const unsigned fg = p * 512 + tid;
        const unsigned row = fg >> 6, c4 = fg & 63;
        *(float4*)&Cg[(size_t)(mblk + c * 64 + row) * N + nblk + c4 * 4] =
            *(const float4*)&Cf[fg * 4];
      }
    }
  }
}

// ---------------- banded / global flash attention (balanced) ----------------
__global__ __launch_bounds__(256) void attn_kernel(const ushort* __restrict__ qkv,
                                                   ushort* __restrict__ outp,
                                                   float* __restrict__ oPart,
                                                   float* __restrict__ mPart,
                                                   float* __restrict__ lPart)
{
  __shared__ __align__(16) ushort Ks[64 * 64];
  __shared__ __align__(16) ushort Vt[64 * 64];
  __shared__ __align__(16) ushort Ps[4][16 * 40];

  const int tid = threadIdx.x;
  const int w = tid >> 6, lane = tid & 63;
  const int lrow = lane & 15, lg = lane >> 4;

  const int bid = (blockIdx.x & 7) * 368 + (blockIdx.x >> 3);
  int h, b, bx, kv_lo, kv_hi, chunk = 0;
  bool isGlobal;
  if (bid < 1024) {
    isGlobal = true; h = 0;
    chunk = bid >> 7;
    int qb = bid & 127;
    b = qb >> 5; bx = qb & 31;
    kv_lo = chunk * 256; kv_hi = kv_lo + 256;
  } else {
    isGlobal = false;
    int t = bid - 1024;
    h = 1 + (t >> 7);
    int qb = t & 127;
    b = qb >> 5; bx = qb & 31;
    kv_lo = bx * 64 - 128; if (kv_lo < 0) kv_lo = 0;
    kv_hi = bx * 64 + 192; if (kv_hi > 2048) kv_hi = 2048;
  }
  const int q0b = bx * 64;
  const int q0 = q0b + w * 16;
  const ushort* Qp = qkv + (size_t)b * 2048 * 3072 + h * 64;
  const ushort* Kp = Qp + 1024;
  const ushort* Vp = Qp + 2048;

  s16x8 qf0 = *(const s16x8*)(Qp + (size_t)(q0 + lrow) * 3072 + 8 * lg);
  s16x8 qf1 = *(const s16x8*)(Qp + (size_t)(q0 + lrow) * 3072 + 32 + 8 * lg);

  const f32x4 zero = {0.f, 0.f, 0.f, 0.f};
  f32x4 o[4];
  o[0] = zero; o[1] = zero; o[2] = zero; o[3] = zero;
  float mrun = -3e38f, lsum = 0.f;
  const int q_abs = q0 + lrow;
  const float SCL = 0.18033688011112042f;  // 1/8 * log2(e)

  const int sp = tid >> 3;
  const int sg = tid & 7;
  const int kr0 = tid >> 3;
  const int kc = tid & 7;
  const int vx = (lrow & 7) ^ (lrow >> 3);

  for (int kv = kv_lo; kv < kv_hi; kv += 64) {
    const bool needMask = !isGlobal && (kv < q0b - 64 || kv + 64 > q0b + 128);

    const ushort* vrow = Vp + (size_t)(kv + 2 * sp) * 3072 + 8 * sg;
    s16x8 vlo = *(const s16x8*)vrow;
    s16x8 vhi = *(const s16x8*)(vrow + 3072);

    __syncthreads();

    GLDS(Kp + (size_t)(kv + kr0) * 3072 + 8 * (kc ^ (kr0 & 7)), &Ks[w * 512]);
    GLDS(Kp + (size_t)(kv + 32 + kr0) * 3072 + 8 * (kc ^ (kr0 & 7)), &Ks[2048 + w * 512]);

#pragma unroll
    for (int j = 0; j < 8; j++) {
      const int d = 8 * sg + j;
      const int r = 2 * sp;
      uint pk = (uint)(ushort)vlo[j] | ((uint)(ushort)vhi[j] << 16);
      *(uint*)&Vt[d * 64 + ((((r >> 3) ^ j ^ sg) & 7) << 3) + (r & 7)] = pk;
    }
    __syncthreads();

#pragma unroll
    for (int s = 0; s < 2; s++) {
      const int kb = kv + 32 * s;
      const int rs = 32 * s;
      s16x8 kA0 = *(const s16x8*)&Ks[(rs + lrow) * 64      + ((( lg      ^ (lrow & 7)) & 7) << 3)];
      s16x8 kA1 = *(const s16x8*)&Ks[(rs + lrow) * 64      + ((((4 + lg) ^ (lrow & 7)) & 7) << 3)];
      s16x8 kB0 = *(const s16x8*)&Ks[(rs + 16 + lrow) * 64 + ((( lg      ^ (lrow & 7)) & 7) << 3)];
      s16x8 kB1 = *(const s16x8*)&Ks[(rs + 16 + lrow) * 64 + ((((4 + lg) ^ (lrow & 7)) & 7) << 3)];

      f32x4 sA = __builtin_amdgcn_mfma_f32_16x16x32_bf16(kA0, qf0, zero, 0, 0, 0);
      sA = __builtin_amdgcn_mfma_f32_16x16x32_bf16(kA1, qf1, sA, 0, 0, 0);
      f32x4 sB = __builtin_amdgcn_mfma_f32_16x16x32_bf16(kB0, qf0, zero, 0, 0, 0);
      sB = __builtin_amdgcn_mfma_f32_16x16x32_bf16(kB1, qf1, sB, 0, 0, 0);

      float pA[4], pB[4];
      float rowmax = -3e38f;
      if (needMask) {
#pragma unroll
        for (int i = 0; i < 4; i++) {
          int kaA = kb + 4 * lg + i;
          int dq = q_abs - kaA;
          float va = (dq <= 128 && dq >= -128) ? sA[i] * SCL : -1e30f;
          pA[i] = va; rowmax = fmaxf(rowmax, va);
          int dqb = dq - 16;
          float vb = (dqb <= 128 && dqb >= -128) ? sB[i] * SCL : -1e30f;
          pB[i] = vb; rowmax = fmaxf(rowmax, vb);
        }
      } else {
#pragma unroll
        for (int i = 0; i < 4; i++) {
          pA[i] = sA[i] * SCL; pB[i] = sB[i] * SCL;
          rowmax = fmaxf(rowmax, fmaxf(pA[i], pB[i]));
        }
      }
      rowmax = fmaxf(rowmax, __shfl_xor(rowmax, 16));
      rowmax = fmaxf(rowmax, __shfl_xor(rowmax, 32));

      if (!__all(rowmax <= mrun + 8.f)) {
        float mnew = fmaxf(mrun, rowmax);
        float alpha = exp2f(mrun - mnew);
        mrun = mnew;
        lsum *= alpha;
        float a0 = __shfl(alpha, 4 * lg + 0);
        float a1 = __shfl(alpha, 4 * lg + 1);
        float a2 = __shfl(alpha, 4 * lg + 2);
        float a3 = __shfl(alpha, 4 * lg + 3);
#pragma unroll
        for (int c = 0; c < 4; c++) {
          o[c][0] *= a0; o[c][1] *= a1; o[c][2] *= a2; o[c][3] *= a3;
        }
      }

      float rsum = 0.f;
      if (needMask) {
#pragma unroll
        for (int i = 0; i < 4; i++) {
          pA[i] = (pA[i] > -1e29f) ? exp2f(pA[i] - mrun) : 0.f;
          pB[i] = (pB[i] > -1e29f) ? exp2f(pB[i] - mrun) : 0.f;
          rsum += pA[i] + pB[i];
        }
      } else {
#pragma unroll
        for (int i = 0; i < 4; i++) {
          pA[i] = exp2f(pA[i] - mrun);
          pB[i] = exp2f(pB[i] - mrun);
          rsum += pA[i] + pB[i];
        }
      }
      rsum += __shfl_xor(rsum, 16);
      rsum += __shfl_xor(rsum, 32);
      lsum += rsum;

      {
        ushort* P = &Ps[w][lrow * 40];
        *(uint*)&P[4 * lg]      = (uint)f2bf(pA[0]) | ((uint)f2bf(pA[1]) << 16);
        *(uint*)&P[4 * lg + 2]  = (uint)f2bf(pA[2]) | ((uint)f2bf(pA[3]) << 16);
        *(uint*)&P[16 + 4 * lg] = (uint)f2bf(pB[0]) | ((uint)f2bf(pB[1]) << 16);
        *(uint*)&P[18 + 4 * lg] = (uint)f2bf(pB[2]) | ((uint)f2bf(pB[3]) << 16);
      }
      s16x8 paf = *(const s16x8*)&Ps[w][lrow * 40 + 8 * lg];

#pragma unroll
      for (int c = 0; c < 4; c++) {
        const int d = 16 * c + lrow;
        s16x8 vf = *(const s16x8*)&Vt[d * 64 + ((((4 * s + lg) ^ vx ^ (2 * c)) & 7) << 3)];
        o[c] = __builtin_amdgcn_mfma_f32_16x16x32_bf16(paf, vf, o[c], 0, 0, 0);
      }
    }
  }

  if (isGlobal) {
    const size_t rbase = (size_t)(chunk * 4 + b) * 2048 + q0;
    if (lg == 0) {
      mPart[rbase + lrow] = mrun;
      lPart[rbase + lrow] = lsum;
    }
#pragma unroll
    for (int c = 0; c < 4; c++)
#pragma unroll
      for (int i = 0; i < 4; i++)
        oPart[(rbase + 4 * lg + i) * 64 + 16 * c + lrow] = o[c][i];
  } else {
    float li0 = 1.f / __shfl(lsum, 4 * lg + 0);
    float li1 = 1.f / __shfl(lsum, 4 * lg + 1);
    float li2 = 1.f / __shfl(lsum, 4 * lg + 2);
    float li3 = 1.f / __shfl(lsum, 4 * lg + 3);
    size_t orow = (size_t)(b * 2048 + q0 + 4 * lg);
#pragma unroll
    for (int c = 0; c < 4; c++) {
      outp[(orow + 0) * 1024 + h * 64 + 16 * c + lrow] = f2bf(o[c][0] * li0);
      outp[(orow + 1) * 1024 + h * 64 + 16 * c + lrow] = f2bf(o[c][1] * li1);
      outp[(orow + 2) * 1024 + h * 64 + 16 * c + lrow] = f2bf(o[c][2] * li2);
      outp[(orow + 3) * 1024 + h * 64 + 16 * c + lrow] = f2bf(o[c][3] * li3);
    }
  }
}

// ---------------- combine global-head partials ----------------
__global__ __launch_bounds__(256) void combine_kernel(const float* __restrict__ oPart,
                                                      const float* __restrict__ mPart,
                                                      const float* __restrict__ lPart,
                                                      ushort* __restrict__ attno) {
  const int tid = threadIdx.x;
  const int row = blockIdx.x * 64 + (tid >> 2);
  const int d0 = (tid & 3) * 16;
  float m[8], l[8], M = -3e38f;
#pragma unroll
  for (int p = 0; p < 8; p++) {
    m[p] = mPart[p * 8192 + row];
    l[p] = lPart[p * 8192 + row];
    M = fmaxf(M, m[p]);
  }
  float L = 0.f, wgt[8];
#pragma unroll
  for (int p = 0; p < 8; p++) { wgt[p] = exp2f(m[p] - M); L += wgt[p] * l[p]; }
  float inv = 1.f / L;
  float acc[16];
#pragma unroll
  for (int j = 0; j < 16; j++) acc[j] = 0.f;
#pragma unroll
  for (int p = 0; p < 8; p++) {
    const float* op = oPart + ((size_t)p * 8192 + row) * 64 + d0;
    float wv = wgt[p];
#pragma unroll
    for (int j = 0; j < 16; j += 4) {
      float4 v = *(const float4*)(op + j);
      acc[j]     += wv * v.x; acc[j + 1] += wv * v.y;
      acc[j + 2] += wv * v.z; acc[j + 3] += wv * v.w;
    }
  }
  ushort* dst = attno + (size_t)row * 1024 + d0;
#pragma unroll
  for (int j = 0; j < 16; j++) dst[j] = f2bf(acc[j] * inv);
}

// ---------------- launch ----------------
extern "C" void kernel_launch(void* const* d_in, const int* in_sizes, int n_in,
                              void* d_out, int out_size, void* d_ws, size_t ws_size,
                              hipStream_t stream) {
  const float* x  = (const float*)d_in[0];
  const float* wq = (const float*)d_in[1];
  const float* bq = (const float*)d_in[2];
  const float* wk = (const float*)d_in[3];
  const float* bk = (const float*)d_in[4];
  const float* wv = (const float*)d_in[5];
  const float* bv = (const float*)d_in[6];
  const float* wo = (const float*)d_in[7];
  const float* bo = (const float*)d_in[8];

  char* ws = (char*)d_ws;
  ushort* xb    = (ushort*)(ws);                 // 8192x1024 bf16 = 16 MB
  ushort* wqkvb = (ushort*)(ws + 16777216);      // 3072x1024 bf16 =  6 MB
  ushort* wob   = (ushort*)(ws + 23068672);      // 1024x1024 bf16 =  2 MB
  ushort* qkvb  = (ushort*)(ws + 25165824);      // 8192x3072 bf16 = 48 MB
  ushort* attno = (ushort*)(ws + 75497472);      // 8192x1024 bf16 = 16 MB
  float* oPart = (float*)(ws);                   // 8x8192x64 f32 = 16 MB (over xb)
  float* mPart = (float*)(ws + 16777216);
  float* lPart = (float*)(ws + 16777216 + 262144);

  castk<<<8192, 256, 0, stream>>>(x, xb, 8388608);
  castw<<<4096, 256, 0, stream>>>(wq, wk, wv, wo,
                                  wqkvb, wqkvb + 1048576, wqkvb + 2097152, wob);

  // QKV projection: grid 32x12 = 384 blocks (256x256 tiles)
  gemmQ<1><<<384, 512, 0, stream>>>(xb, wqkvb, bq, bk, bv,
                                    (void*)qkvb, 8192, 3072, 1024, 12);

  attn_kernel<<<2944, 256, 0, stream>>>(qkvb, attno, oPart, mPart, lPart);
  combine_kernel<<<128, 256, 0, stream>>>(oPart, mPart, lPart, attno);

  // output projection: grid 32x4 = 128 blocks, f32 out
  gemmQ<0><<<128, 512, 0, stream>>>(attno, wob, bo, nullptr, nullptr,
                                    (void*)d_out, 8192, 1024, 1024, 4);
}